// Round 1
// baseline (241.121 us; speedup 1.0000x reference)
//
#include <hip/hip_runtime.h>

#define BATCH 16
#define CIN   128
#define HIMG  56
#define WIMG  56
#define NPIX  (HIMG*WIMG)      // 3136
#define CS    256
#define HPAR  8                // hp = N_HEADS*STRIDE
#define HCH   32               // hc
#define NQ    4
#define HOUT  28
#define WOUT  28
#define NOPIX (HOUT*WOUT)      // 784
#define QSCALE 0.17677669529663687f   // hc^-0.5 = 1/sqrt(32)

// ---------- kernel 0: transpose Wout (o,c) -> WoutT (c,o) ----------
__global__ __launch_bounds__(256) void k0_transpose(const float* __restrict__ Wout,
                                                    float* __restrict__ WoutT) {
    const int c = blockIdx.x, o = threadIdx.x;
    WoutT[c*CS + o] = Wout[o*CS + c];
}

// ---------- kernel 1: K/V = x^T @ (Wk|Wv), cost = exp(q . K) ----------
// x: (B, C, N)  -> per-pixel K,V (Cs each). Stores V (B*N,256) and cost (B*N,32).
#define PT1 32
__global__ __launch_bounds__(256) void k1_kv_cost(
    const float* __restrict__ x, const float* __restrict__ Wk,
    const float* __restrict__ Wv, const float* __restrict__ qp,
    float* __restrict__ costO, float* __restrict__ Vout)
{
    __shared__ __align__(16) float xt[CIN][PT1];   // 16 KB
    __shared__ __align__(16) float kt[PT1][CS];    // 32 KB
    __shared__ float qs[NQ*CS];                    // 4 KB

    const int t   = threadIdx.x;
    const int blk = blockIdx.x;
    const int b   = blk / (NPIX/PT1);
    const int p0  = (blk % (NPIX/PT1)) * PT1;

    for (int i = t; i < NQ*CS; i += 256) qs[i] = qp[i] * QSCALE;

    {   // stage x tile, coalesced float4 (N=3136 divisible by 32, rows 16B-aligned)
        const int r  = t >> 3;      // 0..31
        const int l4 = t & 7;       // 8 float4 per 32-float row
        #pragma unroll
        for (int pass = 0; pass < 4; ++pass) {
            const int c = r + pass*32;
            const float4 v = *(const float4*)(x + ((size_t)b*CIN + c)*NPIX + p0 + l4*4);
            *(float4*)&xt[c][l4*4] = v;
        }
    }
    __syncthreads();

    float accK[PT1], accV[PT1];
    #pragma unroll
    for (int p = 0; p < PT1; ++p) { accK[p] = 0.f; accV[p] = 0.f; }

    const int cs = t;   // output channel owned by this thread
    for (int c = 0; c < CIN; ++c) {
        const float wk = Wk[c*CS + cs];
        const float wv = Wv[c*CS + cs];
        #pragma unroll
        for (int p4 = 0; p4 < PT1; p4 += 4) {
            const float4 xv = *(const float4*)&xt[c][p4];  // broadcast read
            accK[p4+0] = fmaf(xv.x, wk, accK[p4+0]);
            accK[p4+1] = fmaf(xv.y, wk, accK[p4+1]);
            accK[p4+2] = fmaf(xv.z, wk, accK[p4+2]);
            accK[p4+3] = fmaf(xv.w, wk, accK[p4+3]);
            accV[p4+0] = fmaf(xv.x, wv, accV[p4+0]);
            accV[p4+1] = fmaf(xv.y, wv, accV[p4+1]);
            accV[p4+2] = fmaf(xv.z, wv, accV[p4+2]);
            accV[p4+3] = fmaf(xv.w, wv, accV[p4+3]);
        }
    }

    #pragma unroll
    for (int p = 0; p < PT1; ++p) {
        Vout[((size_t)(b*NPIX) + p0 + p)*CS + cs] = accV[p];   // coalesced
        kt[p][cs] = accK[p];
    }
    __syncthreads();

    // cost[p][qh] = exp( sum_c qs[q][h*32+c] * K[p][h*32+c] )
    const int qh = t & 31;
    const int h  = qh & 7, q = qh >> 3;
    const int pb = t >> 5;
    #pragma unroll
    for (int rep = 0; rep < 4; ++rep) {
        const int p = pb + rep*8;
        const float* kr = &kt[p][h*HCH];
        const float* qr = &qs[q*CS + h*HCH];
        float dot = 0.f;
        #pragma unroll
        for (int c = 0; c < HCH; ++c) dot = fmaf(kr[c], qr[c], dot);
        costO[((size_t)(b*NPIX) + p0 + p)*32 + qh] = __expf(dot);
    }
}

// ---------- kernel 2: per-output-pixel 9-tap aggregation ----------
// pre[h*32+c] = sum_k coef[k][h] * V[p_k][h*32+c]
// coef[k][h]  = sum_q exp(rpb[k,qh])*attn_scale[k,qh]*cost[p_k,qh] / den[qh]
__global__ __launch_bounds__(256) void k2_agg(
    const float* __restrict__ cost, const float* __restrict__ V,
    const float* __restrict__ ascale, const float* __restrict__ rpb,
    float* __restrict__ pre)
{
    __shared__ float part[9][32];
    __shared__ float coef[9][8];

    const int blk = blockIdx.x;           // b*784 + ho*28 + wo
    const int b   = blk / NOPIX;
    const int rem = blk % NOPIX;
    const int ho  = rem / WOUT, wo = rem % WOUT;
    const int t   = threadIdx.x;

    int pk[9];
    #pragma unroll
    for (int k = 0; k < 9; ++k) {
        const int ki = k / 3, kj = k % 3;
        const int y  = 2*ho - 1 + ki;
        const int xx = 2*wo - 1 + kj;
        const bool v = ((unsigned)y < (unsigned)HIMG) && ((unsigned)xx < (unsigned)WIMG);
        pk[k] = v ? (y*WIMG + xx) : -1;
    }

    if (t < 32) {
        const int qh = t;
        float den = 0.f;
        float cp[9];
        #pragma unroll
        for (int k = 0; k < 9; ++k) {
            const float s  = (pk[k] >= 0) ? cost[((size_t)(b*NPIX) + pk[k])*32 + qh] : 0.f;
            const float wd = __expf(rpb[k*32 + qh]);
            den  += wd * s;
            cp[k] = wd * ascale[k*32 + qh] * s;
        }
        const float rden = 1.f / den;   // den > 0: >=4 valid taps, all terms > 0
        #pragma unroll
        for (int k = 0; k < 9; ++k) part[k][qh] = cp[k] * rden;
    }
    __syncthreads();
    if (t < 72) {
        const int k = t >> 3, h = t & 7;
        coef[k][h] = part[k][h] + part[k][8+h] + part[k][16+h] + part[k][24+h];
    }
    __syncthreads();

    const int h = t >> 5;   // t = channel c2 = h*32+c
    float acc = 0.f;
    #pragma unroll
    for (int k = 0; k < 9; ++k) {
        const int p = (pk[k] >= 0) ? pk[k] : 0;               // coef==0 for invalid taps
        const float vv = V[((size_t)(b*NPIX) + p)*CS + t];    // coalesced 1KB load
        acc = fmaf(coef[k][h], vv, acc);
    }
    pre[(size_t)blk*CS + t] = acc;
}

// ---------- kernel 3: out = Wout @ pre  (per-pixel 256x256 matvec as GEMM) ----------
#define PT3 16
__global__ __launch_bounds__(256) void k3_proj(
    const float* __restrict__ pre, const float* __restrict__ WoutT,
    float* __restrict__ out)
{
    __shared__ __align__(16) float pt[PT3][CS];    // 16 KB, [pixel][channel]
    const int t   = threadIdx.x;
    const int g0  = blockIdx.x * PT3;              // global out-pixel base (never crosses batch: 784 = 49*16)
    const int b   = g0 / NOPIX;
    const int op0 = g0 % NOPIX;

    #pragma unroll
    for (int p = 0; p < PT3; ++p)
        pt[p][t] = pre[((size_t)g0 + p)*CS + t];   // coalesced; 2-way LDS (free)
    __syncthreads();

    const int o = t;
    float acc[PT3];
    #pragma unroll
    for (int p = 0; p < PT3; ++p) acc[p] = 0.f;

    for (int c4 = 0; c4 < CS; c4 += 4) {
        const float w0 = WoutT[(c4+0)*CS + o];     // coalesced
        const float w1 = WoutT[(c4+1)*CS + o];
        const float w2 = WoutT[(c4+2)*CS + o];
        const float w3 = WoutT[(c4+3)*CS + o];
        #pragma unroll
        for (int p = 0; p < PT3; ++p) {
            const float4 xv = *(const float4*)&pt[p][c4];   // broadcast b128 read
            acc[p] = fmaf(xv.x, w0, acc[p]);
            acc[p] = fmaf(xv.y, w1, acc[p]);
            acc[p] = fmaf(xv.z, w2, acc[p]);
            acc[p] = fmaf(xv.w, w3, acc[p]);
        }
    }

    float* obase = out + ((size_t)b*CS + o)*NOPIX + op0;   // 16 consecutive floats per thread
    #pragma unroll
    for (int p4 = 0; p4 < PT3; p4 += 4)
        *(float4*)(obase + p4) = make_float4(acc[p4], acc[p4+1], acc[p4+2], acc[p4+3]);
}

extern "C" void kernel_launch(void* const* d_in, const int* in_sizes, int n_in,
                              void* d_out, int out_size, void* d_ws, size_t ws_size,
                              hipStream_t stream) {
    const float* x      = (const float*)d_in[0];
    const float* Wk     = (const float*)d_in[1];
    const float* Wv     = (const float*)d_in[2];
    const float* Wout   = (const float*)d_in[3];
    const float* qp     = (const float*)d_in[4];
    const float* ascale = (const float*)d_in[5];
    const float* rpb    = (const float*)d_in[6];
    float* out = (float*)d_out;

    // workspace layout (bytes):
    //   cost : 16*3136*32*4  =  6,422,528
    //   V    : 16*3136*256*4 = 51,380,224
    //   pre  : 12544*256*4   = 12,845,056
    //   WoutT: 256*256*4     =    262,144   (total ~70.9 MB)
    char* ws = (char*)d_ws;
    float* cost  = (float*)(ws);
    float* V     = (float*)(ws + 6422528);
    float* pre   = (float*)(ws + 6422528 + 51380224);
    float* WoutT = (float*)(ws + 6422528 + 51380224 + 12845056);

    k0_transpose<<<CS, 256, 0, stream>>>(Wout, WoutT);
    k1_kv_cost <<<BATCH*(NPIX/PT1), 256, 0, stream>>>(x, Wk, Wv, qp, cost, V);
    k2_agg     <<<BATCH*NOPIX, 256, 0, stream>>>(cost, V, ascale, rpb, pre);
    k3_proj    <<<(BATCH*NOPIX)/PT3, 256, 0, stream>>>(pre, WoutT, out);
}

// Round 2
// 172.144 us; speedup vs baseline: 1.4007x; 1.4007x over previous
//
#include <hip/hip_runtime.h>

#define BATCH 16
#define CIN   128
#define HIMG  56
#define WIMG  56
#define NPIX  (HIMG*WIMG)      // 3136
#define CS    256
#define HPAR  8                // hp = N_HEADS*STRIDE
#define HCH   32               // hc
#define NQ    4
#define HOUT  28
#define WOUT  28
#define NOPIX (HOUT*WOUT)      // 784
#define QSCALE 0.17677669529663687f   // hc^-0.5 = 1/sqrt(32)

// ---------- kernel 0: transpose Wout (o,c) -> WoutT (c,o) ----------
__global__ __launch_bounds__(256) void k0_transpose(const float* __restrict__ Wout,
                                                    float* __restrict__ WoutT) {
    const int c = blockIdx.x, o = threadIdx.x;
    WoutT[c*CS + o] = Wout[o*CS + c];
}

// ---------- kernel 1: K/V = x^T @ (Wk|Wv), cost = exp(q . K) ----------
// Register-tiled: block = 32 pixels x 512 outputs (256 K + 256 V).
// Thread = 8 pixels x 4 channels x {K,V}. x-tile in LDS (broadcast b128 reads),
// weights straight from global (L2-resident, 512 KB total). qk dots reduced
// in-register via shfl_xor across the 8 channel-groups of each head.
#define PIX_BLK 32
__global__ __launch_bounds__(256, 4) void k1_kv_cost(
    const float* __restrict__ x, const float* __restrict__ Wk,
    const float* __restrict__ Wv, const float* __restrict__ qp,
    float* __restrict__ costO, float* __restrict__ Vout)
{
    __shared__ __align__(16) float xt[CIN][36];   // +4 pad: conflict-free staging writes

    const int t   = threadIdx.x;
    const int blk = blockIdx.x;
    const int b   = blk / (NPIX/PIX_BLK);
    const int p0  = (blk % (NPIX/PIX_BLK)) * PIX_BLK;

    {   // stage x tile (128 rows x 32 floats), coalesced float4
        const int r  = t >> 3;      // 0..31
        const int l4 = t & 7;       // 8 float4 per 32-float row
        #pragma unroll
        for (int pass = 0; pass < 4; ++pass) {
            const int c = r + pass*32;
            const float4 v = *(const float4*)(x + ((size_t)b*CIN + c)*NPIX + p0 + l4*4);
            *(float4*)&xt[c][l4*4] = v;
        }
    }
    __syncthreads();

    const int cgrp = t & 63;        // 64 groups x 4 channels
    const int pgrp = t >> 6;        // 4 groups x 8 pixels
    const int ch0  = cgrp * 4;
    const int prow = pgrp * 8;

    float accK[8][4], accV[8][4];
    #pragma unroll
    for (int i = 0; i < 8; ++i)
        #pragma unroll
        for (int j = 0; j < 4; ++j) { accK[i][j] = 0.f; accV[i][j] = 0.f; }

    const float* wkp = Wk + ch0;
    const float* wvp = Wv + ch0;

    #pragma unroll 2
    for (int c = 0; c < CIN; ++c) {
        const float4 wk = *(const float4*)(wkp + (size_t)c*CS);   // L2-hit, coalesced
        const float4 wv = *(const float4*)(wvp + (size_t)c*CS);
        const float4 xa = *(const float4*)&xt[c][prow];           // broadcast b128
        const float4 xb = *(const float4*)&xt[c][prow+4];
        const float xv[8] = {xa.x, xa.y, xa.z, xa.w, xb.x, xb.y, xb.z, xb.w};
        #pragma unroll
        for (int i = 0; i < 8; ++i) {
            accK[i][0] = fmaf(xv[i], wk.x, accK[i][0]);
            accK[i][1] = fmaf(xv[i], wk.y, accK[i][1]);
            accK[i][2] = fmaf(xv[i], wk.z, accK[i][2]);
            accK[i][3] = fmaf(xv[i], wk.w, accK[i][3]);
            accV[i][0] = fmaf(xv[i], wv.x, accV[i][0]);
            accV[i][1] = fmaf(xv[i], wv.y, accV[i][1]);
            accV[i][2] = fmaf(xv[i], wv.z, accV[i][2]);
            accV[i][3] = fmaf(xv[i], wv.w, accV[i][3]);
        }
    }

    // ---- store V (coalesced: 64 lanes x float4 = 1KB per pixel row) ----
    #pragma unroll
    for (int i = 0; i < 8; ++i) {
        float4 v4 = make_float4(accV[i][0], accV[i][1], accV[i][2], accV[i][3]);
        *(float4*)(Vout + ((size_t)(b*NPIX) + p0 + prow + i)*CS + ch0) = v4;
    }

    // ---- cost = exp(q . K), dot reduced across the 8 ch-groups of this head ----
    float q4[NQ][4];
    #pragma unroll
    for (int q = 0; q < NQ; ++q) {
        const float4 qv = *(const float4*)(qp + q*CS + ch0);
        q4[q][0] = qv.x*QSCALE; q4[q][1] = qv.y*QSCALE;
        q4[q][2] = qv.z*QSCALE; q4[q][3] = qv.w*QSCALE;
    }
    float d[8][NQ];
    #pragma unroll
    for (int i = 0; i < 8; ++i)
        #pragma unroll
        for (int q = 0; q < NQ; ++q) {
            float s = accK[i][0]*q4[q][0];
            s = fmaf(accK[i][1], q4[q][1], s);
            s = fmaf(accK[i][2], q4[q][2], s);
            s = fmaf(accK[i][3], q4[q][3], s);
            d[i][q] = s;
        }
    #pragma unroll
    for (int mask = 1; mask <= 4; mask <<= 1)
        #pragma unroll
        for (int i = 0; i < 8; ++i)
            #pragma unroll
            for (int q = 0; q < NQ; ++q)
                d[i][q] += __shfl_xor(d[i][q], mask);

    const int h = cgrp >> 3;        // head 0..7
    const int r = cgrp & 7;         // this lane stores pixel prow+r
    float* cbase = costO + ((size_t)(b*NPIX) + p0 + prow + r)*32 + h;
    #pragma unroll
    for (int i = 0; i < 8; ++i) {   // static index; predicated on i==r (rule #20)
        if (i == r) {
            #pragma unroll
            for (int q = 0; q < NQ; ++q)
                cbase[q*8] = __expf(d[i][q]);
        }
    }
}

// ---------- kernel 2: per-output-pixel 9-tap aggregation ----------
__global__ __launch_bounds__(256) void k2_agg(
    const float* __restrict__ cost, const float* __restrict__ V,
    const float* __restrict__ ascale, const float* __restrict__ rpb,
    float* __restrict__ pre)
{
    __shared__ float part[9][32];
    __shared__ float coef[9][8];

    const int blk = blockIdx.x;           // b*784 + ho*28 + wo
    const int b   = blk / NOPIX;
    const int rem = blk % NOPIX;
    const int ho  = rem / WOUT, wo = rem % WOUT;
    const int t   = threadIdx.x;

    int pk[9];
    #pragma unroll
    for (int k = 0; k < 9; ++k) {
        const int ki = k / 3, kj = k % 3;
        const int y  = 2*ho - 1 + ki;
        const int xx = 2*wo - 1 + kj;
        const bool v = ((unsigned)y < (unsigned)HIMG) && ((unsigned)xx < (unsigned)WIMG);
        pk[k] = v ? (y*WIMG + xx) : -1;
    }

    if (t < 32) {
        const int qh = t;
        float den = 0.f;
        float cp[9];
        #pragma unroll
        for (int k = 0; k < 9; ++k) {
            const float s  = (pk[k] >= 0) ? cost[((size_t)(b*NPIX) + pk[k])*32 + qh] : 0.f;
            const float wd = __expf(rpb[k*32 + qh]);
            den  += wd * s;
            cp[k] = wd * ascale[k*32 + qh] * s;
        }
        const float rden = 1.f / den;
        #pragma unroll
        for (int k = 0; k < 9; ++k) part[k][qh] = cp[k] * rden;
    }
    __syncthreads();
    if (t < 72) {
        const int k = t >> 3, h = t & 7;
        coef[k][h] = part[k][h] + part[k][8+h] + part[k][16+h] + part[k][24+h];
    }
    __syncthreads();

    const int h = t >> 5;
    float acc = 0.f;
    #pragma unroll
    for (int k = 0; k < 9; ++k) {
        const int p = (pk[k] >= 0) ? pk[k] : 0;
        const float vv = V[((size_t)(b*NPIX) + p)*CS + t];
        acc = fmaf(coef[k][h], vv, acc);
    }
    pre[(size_t)blk*CS + t] = acc;
}

// ---------- kernel 3: out = Wout @ pre ----------
#define PT3 16
__global__ __launch_bounds__(256) void k3_proj(
    const float* __restrict__ pre, const float* __restrict__ WoutT,
    float* __restrict__ out)
{
    __shared__ __align__(16) float pt[PT3][CS];
    const int t   = threadIdx.x;
    const int g0  = blockIdx.x * PT3;
    const int b   = g0 / NOPIX;
    const int op0 = g0 % NOPIX;

    #pragma unroll
    for (int p = 0; p < PT3; ++p)
        pt[p][t] = pre[((size_t)g0 + p)*CS + t];
    __syncthreads();

    const int o = t;
    float acc[PT3];
    #pragma unroll
    for (int p = 0; p < PT3; ++p) acc[p] = 0.f;

    for (int c4 = 0; c4 < CS; c4 += 4) {
        const float w0 = WoutT[(c4+0)*CS + o];
        const float w1 = WoutT[(c4+1)*CS + o];
        const float w2 = WoutT[(c4+2)*CS + o];
        const float w3 = WoutT[(c4+3)*CS + o];
        #pragma unroll
        for (int p = 0; p < PT3; ++p) {
            const float4 xv = *(const float4*)&pt[p][c4];
            acc[p] = fmaf(xv.x, w0, acc[p]);
            acc[p] = fmaf(xv.y, w1, acc[p]);
            acc[p] = fmaf(xv.z, w2, acc[p]);
            acc[p] = fmaf(xv.w, w3, acc[p]);
        }
    }

    float* obase = out + ((size_t)b*CS + o)*NOPIX + op0;
    #pragma unroll
    for (int p4 = 0; p4 < PT3; p4 += 4)
        *(float4*)(obase + p4) = make_float4(acc[p4], acc[p4+1], acc[p4+2], acc[p4+3]);
}

extern "C" void kernel_launch(void* const* d_in, const int* in_sizes, int n_in,
                              void* d_out, int out_size, void* d_ws, size_t ws_size,
                              hipStream_t stream) {
    const float* x      = (const float*)d_in[0];
    const float* Wk     = (const float*)d_in[1];
    const float* Wv     = (const float*)d_in[2];
    const float* Wout   = (const float*)d_in[3];
    const float* qp     = (const float*)d_in[4];
    const float* ascale = (const float*)d_in[5];
    const float* rpb    = (const float*)d_in[6];
    float* out = (float*)d_out;

    char* ws = (char*)d_ws;
    float* cost  = (float*)(ws);
    float* V     = (float*)(ws + 6422528);
    float* pre   = (float*)(ws + 6422528 + 51380224);
    float* WoutT = (float*)(ws + 6422528 + 51380224 + 12845056);

    k0_transpose<<<CS, 256, 0, stream>>>(Wout, WoutT);
    k1_kv_cost <<<BATCH*(NPIX/PIX_BLK), 256, 0, stream>>>(x, Wk, Wv, qp, cost, V);
    k2_agg     <<<BATCH*NOPIX, 256, 0, stream>>>(cost, V, ascale, rpb, pre);
    k3_proj    <<<(BATCH*NOPIX)/PT3, 256, 0, stream>>>(pre, WoutT, out);
}